// Round 15
// baseline (248.154 us; speedup 1.0000x reference)
//
#include <hip/hip_runtime.h>
#include <math.h>

#define B_ 32
#define N_ 8192
#define G_ 128
#define K_ 32
#define H_ 128
#define D_ 384
#define CAP_ 1024

#define CEN_OFF (B_ * G_ * D_)
#define GIDX_OFF (B_ * G_ * D_ + B_ * G_ * 3)

typedef short bf16x8 __attribute__((ext_vector_type(8)));
typedef float f32x4 __attribute__((ext_vector_type(4)));

__device__ __forceinline__ unsigned short f2bf(float x) {
    unsigned u = __float_as_uint(x);
    u += 0x7FFFu + ((u >> 16) & 1u);
    return (unsigned short)(u >> 16);
}
__device__ __forceinline__ float bf2f(unsigned short h) {
    return __uint_as_float(((unsigned)h) << 16);
}

// Wave-wide max broadcast to all 64 lanes. DPP row_ror 1/2/4/8 (VALU-only,
// no LGKM wait) covers each 16-lane row; ds_swizzle xor16 + shfl_xor32 finish.
__device__ __forceinline__ float wave_max_f(float v) {
    int b;
    b = __builtin_amdgcn_update_dpp(0, __float_as_int(v), 0x121, 0xf, 0xf, false);
    v = fmaxf(v, __int_as_float(b));
    b = __builtin_amdgcn_update_dpp(0, __float_as_int(v), 0x122, 0xf, 0xf, false);
    v = fmaxf(v, __int_as_float(b));
    b = __builtin_amdgcn_update_dpp(0, __float_as_int(v), 0x124, 0xf, 0xf, false);
    v = fmaxf(v, __int_as_float(b));
    b = __builtin_amdgcn_update_dpp(0, __float_as_int(v), 0x128, 0xf, 0xf, false);
    v = fmaxf(v, __int_as_float(b));
    b = __builtin_amdgcn_ds_swizzle(__float_as_int(v), 0x401F);   // lane ^ 16
    v = fmaxf(v, __int_as_float(b));
    v = fmaxf(v, __shfl_xor(v, 32));                              // lane ^ 32
    return v;
}

// 4 consecutive points (48B = 3 float4) -> 4 squared distances.
// SAME inline used in both knn passes => identical codegen => bit-identical d.
__device__ __forceinline__ void dist4(const float* __restrict__ p,
                                      float cx, float cy, float cz,
                                      float* __restrict__ o) {
    const float4 f0 = *(const float4*)(p);
    const float4 f1 = *(const float4*)(p + 4);
    const float4 f2 = *(const float4*)(p + 8);
    {
        const float dx = f0.x - cx, dy = f0.y - cy, dz = f0.z - cz;
        o[0] = dx * dx + dy * dy + dz * dz;
    }
    {
        const float dx = f0.w - cx, dy = f1.x - cy, dz = f1.y - cz;
        o[1] = dx * dx + dy * dy + dz * dz;
    }
    {
        const float dx = f1.z - cx, dy = f1.w - cy, dz = f2.x - cz;
        o[2] = dx * dx + dy * dy + dz * dz;
    }
    {
        const float dx = f2.y - cx, dy = f2.z - cy, dz = f2.w - cz;
        o[3] = dx * dx + dy * dy + dz * dz;
    }
}

// ---------------- Kernel 0: W2 -> hi/lo bf16 fragments (gather form) ----------------

__global__ __launch_bounds__(512) void prep_kernel(
    const float* __restrict__ W2,
    unsigned short* __restrict__ w2hi,
    unsigned short* __restrict__ w2lo)
{
    const int o = blockIdx.x * 512 + threadIdx.x;   // 0..49151
    const int q = o >> 9;
    const int l = (o >> 3) & 63;
    const int e = o & 7;
    const int c = ((q >> 2) << 4) | (l & 15);
    const int j = ((q & 3) << 5) | (((l >> 4) & 3) << 3) | e;
    const float w = W2[j * D_ + c];
    const unsigned short hi = f2bf(w);
    w2hi[o] = hi;
    w2lo[o] = f2bf(w - bf2f(hi));
}

// ---------------- Kernel 1: FPS (byte-identical to rounds 9/11/12) ----------------

#define FPT 16

__global__ __launch_bounds__(512) void fps_kernel(
    const float* __restrict__ xyz,
    float* __restrict__ centers_out,
    int* __restrict__ cidx)
{
    __shared__ float sxx[N_], syy[N_], szz[N_];     // 96 KB SoA xyz cache
    __shared__ double sred[3][8];
    __shared__ float smean[3];
    __shared__ unsigned long long skey[3];

    const int b    = blockIdx.x;
    const int tid  = threadIdx.x;
    const int lane = tid & 63;
    const int wid  = tid >> 6;
    const float* base = xyz + (size_t)b * N_ * 3;

    float lx[FPT], ly[FPT], lz[FPT];
    double sx = 0.0, sy = 0.0, sz = 0.0;
#pragma unroll
    for (int r = 0; r < FPT; ++r) {
        const int i = tid + r * 512;
        lx[r] = base[i * 3 + 0];
        ly[r] = base[i * 3 + 1];
        lz[r] = base[i * 3 + 2];
        sxx[i] = lx[r]; syy[i] = ly[r]; szz[i] = lz[r];
        sx += lx[r]; sy += ly[r]; sz += lz[r];
    }
#pragma unroll
    for (int off = 32; off >= 1; off >>= 1) {
        sx += __shfl_xor(sx, off);
        sy += __shfl_xor(sy, off);
        sz += __shfl_xor(sz, off);
    }
    if (lane == 0) { sred[0][wid] = sx; sred[1][wid] = sy; sred[2][wid] = sz; }
    if (tid == 0) { skey[0] = 0ULL; skey[1] = 0ULL; skey[2] = 0ULL; }
    __syncthreads();
    if (tid == 0) {
        double tx = 0, ty = 0, tz = 0;
        for (int w = 0; w < 8; ++w) { tx += sred[0][w]; ty += sred[1][w]; tz += sred[2][w]; }
        smean[0] = (float)(tx / (double)N_);
        smean[1] = (float)(ty / (double)N_);
        smean[2] = (float)(tz / (double)N_);
    }
    __syncthreads();
    float cx = smean[0], cy = smean[1], cz = smean[2];

    float dm[FPT];
#pragma unroll
    for (int r = 0; r < FPT; ++r) dm[r] = 1e10f;

    int far;

#define TREE16(A, OUT)                                                          \
    {                                                                           \
        float t0 = fmaxf(A[0], A[1]),  t1 = fmaxf(A[2], A[3]);                  \
        float t2 = fmaxf(A[4], A[5]),  t3 = fmaxf(A[6], A[7]);                  \
        float t4 = fmaxf(A[8], A[9]),  t5 = fmaxf(A[10], A[11]);                \
        float t6 = fmaxf(A[12], A[13]), t7 = fmaxf(A[14], A[15]);               \
        t0 = fmaxf(t0, t1); t2 = fmaxf(t2, t3);                                 \
        t4 = fmaxf(t4, t5); t6 = fmaxf(t6, t7);                                 \
        t0 = fmaxf(t0, t2); t4 = fmaxf(t4, t6);                                 \
        OUT = fmaxf(t0, t4);                                                    \
    }

    // ---- initial: argmax distance-to-mean (slot 2), dm untouched ----
    {
        float dd[FPT];
#pragma unroll
        for (int r = 0; r < FPT; ++r) {
            const float dx = lx[r] - cx, dy = ly[r] - cy, dz = lz[r] - cz;
            dd[r] = fmaf(dz, dz, fmaf(dy, dy, dx * dx));
        }
        float vv; TREE16(dd, vv)
        const float vw = wave_max_f(vv);
        int mi = 0x7FFFFFFF;
#pragma unroll
        for (int r = FPT - 1; r >= 0; --r) if (dd[r] == vw) mi = tid + r * 512;
        if (mi != 0x7FFFFFFF) {
            const unsigned long long key =
                ((unsigned long long)__float_as_uint(vw) << 32) | (unsigned)(8191 - mi);
            atomicMax(&skey[2], key);
        }
        __syncthreads();
        const unsigned long long best = skey[2];
        far = 8191 - (int)(best & 0xFFFFFFFFULL);
        cx = sxx[far]; cy = syy[far]; cz = szz[far];
    }

    for (int t = 0; t < G_; ++t) {
        if (tid == 0) {
            cidx[b * G_ + t] = far;
            const size_t o = ((size_t)(b * G_ + t)) * 3;
            centers_out[o + 0] = cx;
            centers_out[o + 1] = cy;
            centers_out[o + 2] = cz;
        }
        if (t == G_ - 1) break;

#pragma unroll
        for (int r = 0; r < FPT; ++r) {
            const float dx = lx[r] - cx, dy = ly[r] - cy, dz = lz[r] - cz;
            const float d = fmaf(dz, dz, fmaf(dy, dy, dx * dx));
            dm[r] = fminf(dm[r], d);
        }
        float vv; TREE16(dm, vv)
        const float vw = wave_max_f(vv);
        int mi = 0x7FFFFFFF;
#pragma unroll
        for (int r = FPT - 1; r >= 0; --r) if (dm[r] == vw) mi = tid + r * 512;
        if (mi != 0x7FFFFFFF) {
            const unsigned long long key =
                ((unsigned long long)__float_as_uint(vw) << 32) | (unsigned)(8191 - mi);
            atomicMax(&skey[t % 3], key);
        }
        if (tid == 0) skey[(t + 1) % 3] = 0ULL;
        __syncthreads();
        const unsigned long long best = skey[t % 3];
        far = 8191 - (int)(best & 0xFFFFFFFFULL);
        cx = sxx[far]; cy = syy[far]; cz = szz[far];
    }
#undef TREE16
}

// ---------------- Kernel 2: kNN (radix-threshold + rank) + MFMA MLP ----------------
// CHANGE vs r12/r14: d[16] register array ELIMINATED — distances recomputed in
// each consuming pass via the same dist4 inline (bit-identical). Natural VGPR
// demand drops to ~30, so (512, 8) = 4 blocks/CU fits WITHOUT spill.

__global__ __launch_bounds__(512, 8) void knn_mlp_kernel(
    const float* __restrict__ xyz,
    const float* __restrict__ W1, const float* __restrict__ b1,
    const float* __restrict__ b2,
    const int* __restrict__ cidx,
    const unsigned short* __restrict__ w2hi,
    const unsigned short* __restrict__ w2lo,
    float* __restrict__ out)
{
    __shared__ unsigned int hist[2048];
    __shared__ unsigned long long ck[CAP_];
    __shared__ __align__(16) unsigned short AHi[4096];
    __shared__ __align__(16) unsigned short ALo[4096];
    __shared__ float sW1[384], sb1[128];
    __shared__ float relx[K_], rely[K_], relz[K_];
    __shared__ int   ssel[K_];
    __shared__ int   scnt, sT;

    const int bg   = blockIdx.x;
    const int b    = bg >> 7;
    const int tid  = threadIdx.x;
    const int lane = tid & 63;
    const int wid  = tid >> 6;
    const float* base = xyz + (size_t)b * N_ * 3;

    const int ci = cidx[bg];
    const float cx = base[ci * 3 + 0];
    const float cy = base[ci * 3 + 1];
    const float cz = base[ci * 3 + 2];

    for (int i = tid; i < 2048; i += 512) hist[i] = 0u;
    if (tid < 384) sW1[tid] = W1[tid];
    else if (tid < 512 && tid >= 384) sb1[tid - 384] = b1[tid - 384];
    if (tid == 0) scnt = 0;
    __syncthreads();

    // Pass A: load -> dist -> histogram immediately (no d[] storage).
#pragma unroll
    for (int q = 0; q < 4; ++q) {
        float dd[4];
        dist4(base + q * 6144 + tid * 12, cx, cy, cz, dd);
#pragma unroll
        for (int e = 0; e < 4; ++e)
            atomicAdd(&hist[__float_as_uint(dd[e]) >> 21], 1u);
    }
    __syncthreads();

    if (tid < 64) {
        const uint4* h4 = (const uint4*)hist;
        unsigned c = 0;
#pragma unroll
        for (int m = 0; m < 8; ++m) {
            const uint4 v = h4[tid * 8 + m];
            c += v.x + v.y + v.z + v.w;
        }
        unsigned cum = c;
#pragma unroll
        for (int off = 1; off < 64; off <<= 1) {
            const unsigned o = __shfl_up(cum, off);
            if (lane >= off) cum += o;
        }
        const unsigned long long mask = __ballot(cum >= (unsigned)K_);
        const int chunk = __ffsll(mask) - 1;
        const unsigned prior = (chunk > 0) ? (unsigned)__shfl((int)cum, chunk - 1) : 0u;
        const unsigned h2 = hist[chunk * 32 + (lane & 31)];
        unsigned cum2 = h2;
#pragma unroll
        for (int off = 1; off < 32; off <<= 1) {
            const unsigned o = __shfl_up(cum2, off);
            if ((lane & 31) >= off) cum2 += o;
        }
        const unsigned long long mask2 = __ballot(prior + cum2 >= (unsigned)K_) & 0xFFFFFFFFULL;
        const int mbin = __ffsll(mask2) - 1;
        if (lane == 0) sT = chunk * 32 + mbin;
    }
    __syncthreads();

    // Pass B: recompute dist (bit-identical), collect candidates <= T.
    const unsigned T = (unsigned)sT;
#pragma unroll
    for (int q = 0; q < 4; ++q) {
        float dd[4];
        dist4(base + q * 6144 + tid * 12, cx, cy, cz, dd);
#pragma unroll
        for (int e = 0; e < 4; ++e) {
            const unsigned bits = __float_as_uint(dd[e]);
            if ((bits >> 21) <= T) {
                const int pos = atomicAdd(&scnt, 1);
                if (pos < CAP_) {
                    const int i = q * 2048 + tid * 4 + e;
                    ck[pos] = ((unsigned long long)bits << 32) | (unsigned)i;
                }
            }
        }
    }
    __syncthreads();

    const int cnt = (scnt < CAP_) ? scnt : CAP_;
    for (int c = tid; c < cnt; c += 512) {
        const unsigned long long kc = ck[c];
        int rk = 0;
        for (int j = 0; j < cnt; ++j) rk += (ck[j] < kc) ? 1 : 0;
        if (rk < K_) ssel[rk] = (int)(kc & 0xFFFFFFFFULL);
    }
    __syncthreads();

    if (tid < K_) {
        const int si = ssel[tid];
        out[GIDX_OFF + (size_t)bg * K_ + tid] = (float)si;
        relx[tid] = base[si * 3 + 0] - cx;
        rely[tid] = base[si * 3 + 1] - cy;
        relz[tid] = base[si * 3 + 2] - cz;
    }
    __syncthreads();

    // ---- h = gelu(rel@W1+b1), computed directly in A-fragment layout ----
    {
        const int p  = wid;
        const int row = ((p >> 2) << 4) + (lane & 15);
        const int j0 = ((p & 3) << 5) + (((lane >> 4) & 3) << 3);
        const float rx = relx[row], ry = rely[row], rz = relz[row];
        bf16x8 hv, lv;
#pragma unroll
        for (int e = 0; e < 8; ++e) {
            const int j = j0 + e;
            const float t = fmaf(rx, sW1[j], fmaf(ry, sW1[128 + j], fmaf(rz, sW1[256 + j], sb1[j])));
            const float g = 0.5f * t * (1.0f + erff(t * 0.70710678118654752f));
            const unsigned short hi = f2bf(g);
            hv[e] = (short)hi;
            lv[e] = (short)f2bf(g - bf2f(hi));
        }
        *(bf16x8*)&AHi[p * 512 + lane * 8] = hv;
        *(bf16x8*)&ALo[p * 512 + lane * 8] = lv;
    }
    __syncthreads();

    // ---- MFMA GEMM: wave w owns N-tiles {3w, 3w+1, 3w+2} ----
    bf16x8 ah[8], al[8];
#pragma unroll
    for (int p = 0; p < 8; ++p) {
        ah[p] = *(const bf16x8*)&AHi[p * 512 + lane * 8];
        al[p] = *(const bf16x8*)&ALo[p * 512 + lane * 8];
    }

#pragma unroll
    for (int nn = 0; nn < 3; ++nn) {
        const int n = wid * 3 + nn;
        f32x4 acc0 = {0.f, 0.f, 0.f, 0.f};
        f32x4 acc1 = {0.f, 0.f, 0.f, 0.f};
#pragma unroll
        for (int kb = 0; kb < 4; ++kb) {
            const int off = (n * 4 + kb) * 512 + lane * 8;
            const bf16x8 bh = *(const bf16x8*)&w2hi[off];
            const bf16x8 bl = *(const bf16x8*)&w2lo[off];
            acc0 = __builtin_amdgcn_mfma_f32_16x16x32_bf16(ah[kb], bh, acc0, 0, 0, 0);
            acc0 = __builtin_amdgcn_mfma_f32_16x16x32_bf16(ah[kb], bl, acc0, 0, 0, 0);
            acc0 = __builtin_amdgcn_mfma_f32_16x16x32_bf16(al[kb], bh, acc0, 0, 0, 0);
            acc1 = __builtin_amdgcn_mfma_f32_16x16x32_bf16(ah[4 + kb], bh, acc1, 0, 0, 0);
            acc1 = __builtin_amdgcn_mfma_f32_16x16x32_bf16(ah[4 + kb], bl, acc1, 0, 0, 0);
            acc1 = __builtin_amdgcn_mfma_f32_16x16x32_bf16(al[4 + kb], bh, acc1, 0, 0, 0);
        }
        float cm = fmaxf(fmaxf(fmaxf(acc0[0], acc0[1]), fmaxf(acc0[2], acc0[3])),
                         fmaxf(fmaxf(acc1[0], acc1[1]), fmaxf(acc1[2], acc1[3])));
        cm = fmaxf(cm, __shfl_xor(cm, 16));
        cm = fmaxf(cm, __shfl_xor(cm, 32));
        if (lane < 16) {
            const int col = n * 16 + lane;
            out[(size_t)bg * D_ + col] = cm + b2[col];
        }
    }
}

// ---------------- launch ----------------

extern "C" void kernel_launch(void* const* d_in, const int* in_sizes, int n_in,
                              void* d_out, int out_size, void* d_ws, size_t ws_size,
                              hipStream_t stream) {
    const float* xyz = (const float*)d_in[0];
    const float* W1  = (const float*)d_in[1];
    const float* b1  = (const float*)d_in[2];
    const float* W2  = (const float*)d_in[3];
    const float* b2  = (const float*)d_in[4];
    float* out = (float*)d_out;

    char* ws = (char*)d_ws;
    int* cidx = (int*)ws;                                        // 16384 B
    unsigned short* w2hi = (unsigned short*)(ws + 16384);        // 98304 B
    unsigned short* w2lo = (unsigned short*)(ws + 16384 + 98304);// 98304 B

    prep_kernel<<<dim3(96), dim3(512), 0, stream>>>(W2, w2hi, w2lo);
    fps_kernel<<<dim3(B_), dim3(512), 0, stream>>>(xyz, out + CEN_OFF, cidx);
    knn_mlp_kernel<<<dim3(B_ * G_), dim3(512), 0, stream>>>(xyz, W1, b1, b2, cidx, w2hi, w2lo, out);
}

// Round 16
// 193.069 us; speedup vs baseline: 1.2853x; 1.2853x over previous
//
#include <hip/hip_runtime.h>
#include <math.h>

#define B_ 32
#define N_ 8192
#define G_ 128
#define K_ 32
#define H_ 128
#define D_ 384
#define CAP_ 1024

#define CEN_OFF (B_ * G_ * D_)
#define GIDX_OFF (B_ * G_ * D_ + B_ * G_ * 3)

typedef short bf16x8 __attribute__((ext_vector_type(8)));
typedef float f32x4 __attribute__((ext_vector_type(4)));

__device__ __forceinline__ unsigned short f2bf(float x) {
    unsigned u = __float_as_uint(x);
    u += 0x7FFFu + ((u >> 16) & 1u);
    return (unsigned short)(u >> 16);
}
__device__ __forceinline__ float bf2f(unsigned short h) {
    return __uint_as_float(((unsigned)h) << 16);
}

// Wave-wide max broadcast to all 64 lanes. DPP row_ror 1/2/4/8 (VALU-only,
// no LGKM wait) covers each 16-lane row; ds_swizzle xor16 + shfl_xor32 finish.
__device__ __forceinline__ float wave_max_f(float v) {
    int b;
    b = __builtin_amdgcn_update_dpp(0, __float_as_int(v), 0x121, 0xf, 0xf, false);
    v = fmaxf(v, __int_as_float(b));
    b = __builtin_amdgcn_update_dpp(0, __float_as_int(v), 0x122, 0xf, 0xf, false);
    v = fmaxf(v, __int_as_float(b));
    b = __builtin_amdgcn_update_dpp(0, __float_as_int(v), 0x124, 0xf, 0xf, false);
    v = fmaxf(v, __int_as_float(b));
    b = __builtin_amdgcn_update_dpp(0, __float_as_int(v), 0x128, 0xf, 0xf, false);
    v = fmaxf(v, __int_as_float(b));
    b = __builtin_amdgcn_ds_swizzle(__float_as_int(v), 0x401F);   // lane ^ 16
    v = fmaxf(v, __int_as_float(b));
    v = fmaxf(v, __shfl_xor(v, 32));                              // lane ^ 32
    return v;
}

// ---------------- Kernel 0: W2 -> hi/lo bf16 fragments (gather form) ----------------

__global__ __launch_bounds__(512) void prep_kernel(
    const float* __restrict__ W2,
    unsigned short* __restrict__ w2hi,
    unsigned short* __restrict__ w2lo)
{
    const int o = blockIdx.x * 512 + threadIdx.x;   // 0..49151
    const int q = o >> 9;
    const int l = (o >> 3) & 63;
    const int e = o & 7;
    const int c = ((q >> 2) << 4) | (l & 15);
    const int j = ((q & 3) << 5) | (((l >> 4) & 3) << 3) | e;
    const float w = W2[j * D_ + c];
    const unsigned short hi = f2bf(w);
    w2hi[o] = hi;
    w2lo[o] = f2bf(w - bf2f(hi));
}

// ---------------- Kernel 1: FPS (byte-identical to rounds 9/11/12) ----------------

#define FPT 16

__global__ __launch_bounds__(512) void fps_kernel(
    const float* __restrict__ xyz,
    float* __restrict__ centers_out,
    int* __restrict__ cidx)
{
    __shared__ float sxx[N_], syy[N_], szz[N_];     // 96 KB SoA xyz cache
    __shared__ double sred[3][8];
    __shared__ float smean[3];
    __shared__ unsigned long long skey[3];

    const int b    = blockIdx.x;
    const int tid  = threadIdx.x;
    const int lane = tid & 63;
    const int wid  = tid >> 6;
    const float* base = xyz + (size_t)b * N_ * 3;

    float lx[FPT], ly[FPT], lz[FPT];
    double sx = 0.0, sy = 0.0, sz = 0.0;
#pragma unroll
    for (int r = 0; r < FPT; ++r) {
        const int i = tid + r * 512;
        lx[r] = base[i * 3 + 0];
        ly[r] = base[i * 3 + 1];
        lz[r] = base[i * 3 + 2];
        sxx[i] = lx[r]; syy[i] = ly[r]; szz[i] = lz[r];
        sx += lx[r]; sy += ly[r]; sz += lz[r];
    }
#pragma unroll
    for (int off = 32; off >= 1; off >>= 1) {
        sx += __shfl_xor(sx, off);
        sy += __shfl_xor(sy, off);
        sz += __shfl_xor(sz, off);
    }
    if (lane == 0) { sred[0][wid] = sx; sred[1][wid] = sy; sred[2][wid] = sz; }
    if (tid == 0) { skey[0] = 0ULL; skey[1] = 0ULL; skey[2] = 0ULL; }
    __syncthreads();
    if (tid == 0) {
        double tx = 0, ty = 0, tz = 0;
        for (int w = 0; w < 8; ++w) { tx += sred[0][w]; ty += sred[1][w]; tz += sred[2][w]; }
        smean[0] = (float)(tx / (double)N_);
        smean[1] = (float)(ty / (double)N_);
        smean[2] = (float)(tz / (double)N_);
    }
    __syncthreads();
    float cx = smean[0], cy = smean[1], cz = smean[2];

    float dm[FPT];
#pragma unroll
    for (int r = 0; r < FPT; ++r) dm[r] = 1e10f;

    int far;

#define TREE16(A, OUT)                                                          \
    {                                                                           \
        float t0 = fmaxf(A[0], A[1]),  t1 = fmaxf(A[2], A[3]);                  \
        float t2 = fmaxf(A[4], A[5]),  t3 = fmaxf(A[6], A[7]);                  \
        float t4 = fmaxf(A[8], A[9]),  t5 = fmaxf(A[10], A[11]);                \
        float t6 = fmaxf(A[12], A[13]), t7 = fmaxf(A[14], A[15]);               \
        t0 = fmaxf(t0, t1); t2 = fmaxf(t2, t3);                                 \
        t4 = fmaxf(t4, t5); t6 = fmaxf(t6, t7);                                 \
        t0 = fmaxf(t0, t2); t4 = fmaxf(t4, t6);                                 \
        OUT = fmaxf(t0, t4);                                                    \
    }

    // ---- initial: argmax distance-to-mean (slot 2), dm untouched ----
    {
        float dd[FPT];
#pragma unroll
        for (int r = 0; r < FPT; ++r) {
            const float dx = lx[r] - cx, dy = ly[r] - cy, dz = lz[r] - cz;
            dd[r] = fmaf(dz, dz, fmaf(dy, dy, dx * dx));
        }
        float vv; TREE16(dd, vv)
        const float vw = wave_max_f(vv);
        int mi = 0x7FFFFFFF;
#pragma unroll
        for (int r = FPT - 1; r >= 0; --r) if (dd[r] == vw) mi = tid + r * 512;
        if (mi != 0x7FFFFFFF) {
            const unsigned long long key =
                ((unsigned long long)__float_as_uint(vw) << 32) | (unsigned)(8191 - mi);
            atomicMax(&skey[2], key);
        }
        __syncthreads();
        const unsigned long long best = skey[2];
        far = 8191 - (int)(best & 0xFFFFFFFFULL);
        cx = sxx[far]; cy = syy[far]; cz = szz[far];
    }

    for (int t = 0; t < G_; ++t) {
        if (tid == 0) {
            cidx[b * G_ + t] = far;
            const size_t o = ((size_t)(b * G_ + t)) * 3;
            centers_out[o + 0] = cx;
            centers_out[o + 1] = cy;
            centers_out[o + 2] = cz;
        }
        if (t == G_ - 1) break;

#pragma unroll
        for (int r = 0; r < FPT; ++r) {
            const float dx = lx[r] - cx, dy = ly[r] - cy, dz = lz[r] - cz;
            const float d = fmaf(dz, dz, fmaf(dy, dy, dx * dx));
            dm[r] = fminf(dm[r], d);
        }
        float vv; TREE16(dm, vv)
        const float vw = wave_max_f(vv);
        int mi = 0x7FFFFFFF;
#pragma unroll
        for (int r = FPT - 1; r >= 0; --r) if (dm[r] == vw) mi = tid + r * 512;
        if (mi != 0x7FFFFFFF) {
            const unsigned long long key =
                ((unsigned long long)__float_as_uint(vw) << 32) | (unsigned)(8191 - mi);
            atomicMax(&skey[t % 3], key);
        }
        if (tid == 0) skey[(t + 1) % 3] = 0ULL;
        __syncthreads();
        const unsigned long long best = skey[t % 3];
        far = 8191 - (int)(best & 0xFFFFFFFFULL);
        cx = sxx[far]; cy = syy[far]; cz = szz[far];
    }
#undef TREE16
}

// ---------------- Kernel 2: kNN (radix-threshold + rank) + MFMA MLP ----------------
// Base = r12 (best measured: d[16] + float4 loads, plain (512) bounds).
// CHANGE: GEMM phase restructured into TWO M-half passes with kb-OUTER loops so
// only 2 A-fragments are live at a time (was 16 = 64 regs parked in AGPRs →
// unified-file demand ~100+ → 2 blocks/CU). Per-accumulator MFMA order is
// unchanged (kb ascending, hi*hi/hi*lo/lo*hi) → bit-identical output.

#define NPT 16  // 8192/512

__global__ __launch_bounds__(512) void knn_mlp_kernel(
    const float* __restrict__ xyz,
    const float* __restrict__ W1, const float* __restrict__ b1,
    const float* __restrict__ b2,
    const int* __restrict__ cidx,
    const unsigned short* __restrict__ w2hi,
    const unsigned short* __restrict__ w2lo,
    float* __restrict__ out)
{
    __shared__ unsigned int hist[2048];
    __shared__ unsigned long long ck[CAP_];
    __shared__ __align__(16) unsigned short AHi[4096];
    __shared__ __align__(16) unsigned short ALo[4096];
    __shared__ float sW1[384], sb1[128];
    __shared__ float relx[K_], rely[K_], relz[K_];
    __shared__ int   ssel[K_];
    __shared__ int   scnt, sT;

    const int bg   = blockIdx.x;
    const int b    = bg >> 7;
    const int tid  = threadIdx.x;
    const int lane = tid & 63;
    const int wid  = tid >> 6;
    const float* base = xyz + (size_t)b * N_ * 3;

    const int ci = cidx[bg];
    const float cx = base[ci * 3 + 0];
    const float cy = base[ci * 3 + 1];
    const float cz = base[ci * 3 + 2];

    for (int i = tid; i < 2048; i += 512) hist[i] = 0u;
    if (tid < 384) sW1[tid] = W1[tid];
    else if (tid < 512 && tid >= 384) sb1[tid - 384] = b1[tid - 384];
    if (tid == 0) scnt = 0;

    // 4 consecutive points per group q: i = q*2048 + tid*4 + e, e=0..3.
    float d[NPT];
#pragma unroll
    for (int q = 0; q < 4; ++q) {
        const float* p = base + q * 6144 + tid * 12;
        const float4 f0 = *(const float4*)(p);
        const float4 f1 = *(const float4*)(p + 4);
        const float4 f2 = *(const float4*)(p + 8);
        {
            const float dx = f0.x - cx, dy = f0.y - cy, dz = f0.z - cz;
            d[q * 4 + 0] = dx * dx + dy * dy + dz * dz;
        }
        {
            const float dx = f0.w - cx, dy = f1.x - cy, dz = f1.y - cz;
            d[q * 4 + 1] = dx * dx + dy * dy + dz * dz;
        }
        {
            const float dx = f1.z - cx, dy = f1.w - cy, dz = f2.x - cz;
            d[q * 4 + 2] = dx * dx + dy * dy + dz * dz;
        }
        {
            const float dx = f2.y - cx, dy = f2.z - cy, dz = f2.w - cz;
            d[q * 4 + 3] = dx * dx + dy * dy + dz * dz;
        }
    }
    __syncthreads();

#pragma unroll
    for (int r = 0; r < NPT; ++r) atomicAdd(&hist[__float_as_uint(d[r]) >> 21], 1u);
    __syncthreads();

    if (tid < 64) {
        const uint4* h4 = (const uint4*)hist;
        unsigned c = 0;
#pragma unroll
        for (int m = 0; m < 8; ++m) {
            const uint4 v = h4[tid * 8 + m];
            c += v.x + v.y + v.z + v.w;
        }
        unsigned cum = c;
#pragma unroll
        for (int off = 1; off < 64; off <<= 1) {
            const unsigned o = __shfl_up(cum, off);
            if (lane >= off) cum += o;
        }
        const unsigned long long mask = __ballot(cum >= (unsigned)K_);
        const int chunk = __ffsll(mask) - 1;
        const unsigned prior = (chunk > 0) ? (unsigned)__shfl((int)cum, chunk - 1) : 0u;
        const unsigned h2 = hist[chunk * 32 + (lane & 31)];
        unsigned cum2 = h2;
#pragma unroll
        for (int off = 1; off < 32; off <<= 1) {
            const unsigned o = __shfl_up(cum2, off);
            if ((lane & 31) >= off) cum2 += o;
        }
        const unsigned long long mask2 = __ballot(prior + cum2 >= (unsigned)K_) & 0xFFFFFFFFULL;
        const int mbin = __ffsll(mask2) - 1;
        if (lane == 0) sT = chunk * 32 + mbin;
    }
    __syncthreads();

    const unsigned T = (unsigned)sT;
#pragma unroll
    for (int r = 0; r < NPT; ++r) {
        const unsigned bits = __float_as_uint(d[r]);
        if ((bits >> 21) <= T) {
            const int pos = atomicAdd(&scnt, 1);
            if (pos < CAP_) {
                const int i = (r >> 2) * 2048 + tid * 4 + (r & 3);
                ck[pos] = ((unsigned long long)bits << 32) | (unsigned)i;
            }
        }
    }
    __syncthreads();

    const int cnt = (scnt < CAP_) ? scnt : CAP_;
    for (int c = tid; c < cnt; c += 512) {
        const unsigned long long kc = ck[c];
        int rk = 0;
        for (int j = 0; j < cnt; ++j) rk += (ck[j] < kc) ? 1 : 0;
        if (rk < K_) ssel[rk] = (int)(kc & 0xFFFFFFFFULL);
    }
    __syncthreads();

    if (tid < K_) {
        const int si = ssel[tid];
        out[GIDX_OFF + (size_t)bg * K_ + tid] = (float)si;
        relx[tid] = base[si * 3 + 0] - cx;
        rely[tid] = base[si * 3 + 1] - cy;
        relz[tid] = base[si * 3 + 2] - cz;
    }
    __syncthreads();

    // ---- h = gelu(rel@W1+b1), computed directly in A-fragment layout ----
    {
        const int p  = wid;
        const int row = ((p >> 2) << 4) + (lane & 15);
        const int j0 = ((p & 3) << 5) + (((lane >> 4) & 3) << 3);
        const float rx = relx[row], ry = rely[row], rz = relz[row];
        bf16x8 hv, lv;
#pragma unroll
        for (int e = 0; e < 8; ++e) {
            const int j = j0 + e;
            const float t = fmaf(rx, sW1[j], fmaf(ry, sW1[128 + j], fmaf(rz, sW1[256 + j], sb1[j])));
            const float g = 0.5f * t * (1.0f + erff(t * 0.70710678118654752f));
            const unsigned short hi = f2bf(g);
            hv[e] = (short)hi;
            lv[e] = (short)f2bf(g - bf2f(hi));
        }
        *(bf16x8*)&AHi[p * 512 + lane * 8] = hv;
        *(bf16x8*)&ALo[p * 512 + lane * 8] = lv;
    }
    __syncthreads();

    // ---- MFMA GEMM: two M-half passes, kb-outer (low live-register set) ----
    // Pass 1: rows 0..15 (A fragment pairs p = kb). Pass 2: rows 16..31 (p = 4+kb).
    float cm0[3], cm1[3];

    {
        f32x4 acc[3] = { {0.f,0.f,0.f,0.f}, {0.f,0.f,0.f,0.f}, {0.f,0.f,0.f,0.f} };
#pragma unroll
        for (int kb = 0; kb < 4; ++kb) {
            const bf16x8 ahk = *(const bf16x8*)&AHi[kb * 512 + lane * 8];
            const bf16x8 alk = *(const bf16x8*)&ALo[kb * 512 + lane * 8];
#pragma unroll
            for (int nn = 0; nn < 3; ++nn) {
                const int n = wid * 3 + nn;
                const int off = (n * 4 + kb) * 512 + lane * 8;
                const bf16x8 bh = *(const bf16x8*)&w2hi[off];
                const bf16x8 bl = *(const bf16x8*)&w2lo[off];
                acc[nn] = __builtin_amdgcn_mfma_f32_16x16x32_bf16(ahk, bh, acc[nn], 0, 0, 0);
                acc[nn] = __builtin_amdgcn_mfma_f32_16x16x32_bf16(ahk, bl, acc[nn], 0, 0, 0);
                acc[nn] = __builtin_amdgcn_mfma_f32_16x16x32_bf16(alk, bh, acc[nn], 0, 0, 0);
            }
        }
#pragma unroll
        for (int nn = 0; nn < 3; ++nn)
            cm0[nn] = fmaxf(fmaxf(acc[nn][0], acc[nn][1]), fmaxf(acc[nn][2], acc[nn][3]));
    }
    {
        f32x4 acc[3] = { {0.f,0.f,0.f,0.f}, {0.f,0.f,0.f,0.f}, {0.f,0.f,0.f,0.f} };
#pragma unroll
        for (int kb = 0; kb < 4; ++kb) {
            const bf16x8 ahk = *(const bf16x8*)&AHi[(4 + kb) * 512 + lane * 8];
            const bf16x8 alk = *(const bf16x8*)&ALo[(4 + kb) * 512 + lane * 8];
#pragma unroll
            for (int nn = 0; nn < 3; ++nn) {
                const int n = wid * 3 + nn;
                const int off = (n * 4 + kb) * 512 + lane * 8;
                const bf16x8 bh = *(const bf16x8*)&w2hi[off];
                const bf16x8 bl = *(const bf16x8*)&w2lo[off];
                acc[nn] = __builtin_amdgcn_mfma_f32_16x16x32_bf16(ahk, bh, acc[nn], 0, 0, 0);
                acc[nn] = __builtin_amdgcn_mfma_f32_16x16x32_bf16(ahk, bl, acc[nn], 0, 0, 0);
                acc[nn] = __builtin_amdgcn_mfma_f32_16x16x32_bf16(alk, bh, acc[nn], 0, 0, 0);
            }
        }
#pragma unroll
        for (int nn = 0; nn < 3; ++nn)
            cm1[nn] = fmaxf(fmaxf(acc[nn][0], acc[nn][1]), fmaxf(acc[nn][2], acc[nn][3]));
    }

#pragma unroll
    for (int nn = 0; nn < 3; ++nn) {
        const int n = wid * 3 + nn;
        float cm = fmaxf(cm0[nn], cm1[nn]);
        cm = fmaxf(cm, __shfl_xor(cm, 16));
        cm = fmaxf(cm, __shfl_xor(cm, 32));
        if (lane < 16) {
            const int col = n * 16 + lane;
            out[(size_t)bg * D_ + col] = cm + b2[col];
        }
    }
}

// ---------------- launch ----------------

extern "C" void kernel_launch(void* const* d_in, const int* in_sizes, int n_in,
                              void* d_out, int out_size, void* d_ws, size_t ws_size,
                              hipStream_t stream) {
    const float* xyz = (const float*)d_in[0];
    const float* W1  = (const float*)d_in[1];
    const float* b1  = (const float*)d_in[2];
    const float* W2  = (const float*)d_in[3];
    const float* b2  = (const float*)d_in[4];
    float* out = (float*)d_out;

    char* ws = (char*)d_ws;
    int* cidx = (int*)ws;                                        // 16384 B
    unsigned short* w2hi = (unsigned short*)(ws + 16384);        // 98304 B
    unsigned short* w2lo = (unsigned short*)(ws + 16384 + 98304);// 98304 B

    prep_kernel<<<dim3(96), dim3(512), 0, stream>>>(W2, w2hi, w2lo);
    fps_kernel<<<dim3(B_), dim3(512), 0, stream>>>(xyz, out + CEN_OFF, cidx);
    knn_mlp_kernel<<<dim3(B_ * G_), dim3(512), 0, stream>>>(xyz, W1, b1, b2, cidx, w2hi, w2lo, out);
}